// Round 10
// baseline (64.511 us; speedup 1.0000x reference)
//
#include <hip/hip_runtime.h>
#include <hip/hip_bf16.h>

typedef __attribute__((ext_vector_type(8))) short s16x8;
typedef __attribute__((ext_vector_type(4))) short s16x4;
typedef __attribute__((ext_vector_type(4))) float fx4;

#define DEVINL __device__ __forceinline__

constexpr int EMBED = 768;
constexpr int HD    = 64;
constexpr int NB    = 16;
constexpr int LEN   = 1024;
constexpr int M_TOT = NB * LEN;   // 16384
constexpr int KVQ   = LEN / 4;    // 256 kv per group in fused attn
constexpr int WELEM = HD * EMBED; // 49152

// fp32 -> bf16 RNE via v_cvt_pk_bf16_f32 (2 elems/inst).
DEVINL unsigned pk2(float lo, float hi) {
  __hip_bfloat162 h = __float22bfloat162_rn(float2{lo, hi});
  union { __hip_bfloat162 h; unsigned u; } c; c.h = h;
  return c.u;
}
DEVINL s16x8 cvt8(fx4 a, fx4 b) {
  union { unsigned u[4]; s16x8 v; } r;
  r.u[0] = pk2(a[0], a[1]); r.u[1] = pk2(a[2], a[3]);
  r.u[2] = pk2(b[0], b[1]); r.u[3] = pk2(b[2], b[3]);
  return r.v;
}
DEVINL s16x4 cvt4(float a0, float a1, float a2, float a3) {
  union { unsigned u[2]; s16x4 v; } r;
  r.u[0] = pk2(a0, a1); r.u[1] = pk2(a2, a3);
  return r.v;
}

DEVINL fx4 mfma16(s16x8 a, s16x8 b, fx4 c) {
  return __builtin_amdgcn_mfma_f32_16x16x32_bf16(a, b, c, 0, 0, 0);
}

// async global->LDS DMA, 16B/lane; dest = wave-uniform base + lane*16,
// source = per-lane address (this is what enables the source-side swizzle).
DEVINL void gload16(const void* g, void* l) {
  __builtin_amdgcn_global_load_lds(
      (const __attribute__((address_space(1))) void*)g,
      (__attribute__((address_space(3))) void*)l, 16, 0, 0);
}

// ---------------------------------------------------------------------------
// One-shot: convert Wq|Wk|Wv (each 64x768 fp32) to bf16, packed [3][49152].
// ---------------------------------------------------------------------------
__global__ __launch_bounds__(256) void convert_w_kernel(
    const float* __restrict__ a, const float* __restrict__ b,
    const float* __restrict__ c, short* __restrict__ out)
{
  const int gid = blockIdx.x * 256 + threadIdx.x;   // 18432 threads, 8 elem each
  const int seg = gid / (WELEM / 8);
  const int off = (gid % (WELEM / 8)) * 8;
  const float* src = (seg == 0) ? a : (seg == 1) ? b : c;
  fx4 v0 = *reinterpret_cast<const fx4*>(src + off);
  fx4 v1 = *reinterpret_cast<const fx4*>(src + off + 4);
  union { unsigned u[4]; s16x8 v; } r;
  r.u[0] = pk2(v0[0], v0[1]); r.u[1] = pk2(v0[2], v0[3]);
  r.u[2] = pk2(v1[0], v1[1]); r.u[3] = pk2(v1[2], v1[3]);
  *reinterpret_cast<s16x8*>(out + (size_t)seg * WELEM + off) = r.v;
}

// ---------------------------------------------------------------------------
// Round-10 projection. Grid 2048 x 512 thr: blocks [0,1024) Q from dec,
// [1024,2048) K+V^T from enc. M=16 rows/block.
//  * X staged fp32 via global_load_lds (48 instr/block -> 48KB in flight;
//    MLP no longer limited by VGPRs). LDS tile [16][4096B] pitch; bank
//    spread via SOURCE-side XOR swizzle (dest is linear per HW constraint),
//    undone at fragment-read time.
//  * W bf16 fragments preloaded into named live registers (Q:12, KV:24) ->
//    allocator must keep them -> loads issue in parallel. L2-resident.
//  * Waves = (quadrant c, K-half g): 12 steps of {2x ds_read_b128 fp32,
//    cvt_pk -> bf16 frag, MFMA}. K-halves reduced via 4-8KB LDS region.
//  * LDS 72KB, launch_bounds(512,4): 2 blocks/CU, VGPR cap 128 (KV ~115).
// ---------------------------------------------------------------------------
__global__ __launch_bounds__(512, 4) void proj_kernel(
    const float* __restrict__ dec, const float* __restrict__ enc,
    const short* __restrict__ wbuf,   // [3][WELEM] bf16: Wq | Wk | Wv
    const float* __restrict__ bq, const float* __restrict__ bk,
    const float* __restrict__ bv,
    short* __restrict__ Qout, short* __restrict__ Kout,
    short* __restrict__ VT)
{
  __shared__ __align__(16) char smem[73728];
  // [0,65536): X tile, 16 rows x 4096B pitch (3072B valid, source-swizzled)
  // [65536,69632): Red1 [16][64] f32   [69632,73728): Red2 [16][64] f32
  float* Red1 = reinterpret_cast<float*>(smem + 65536);
  float* Red2 = reinterpret_cast<float*>(smem + 69632);

  const int t = threadIdx.x, lane = t & 63, w = t >> 6;
  const int c = w & 3, g = w >> 2;          // quadrant, K-half
  const int fr = lane & 15, fg = lane >> 4;
  const bool isQ = blockIdx.x < (unsigned)(M_TOT / 16);
  const int bx = isQ ? blockIdx.x : blockIdx.x - M_TOT / 16;
  const int m0 = bx * 16;
  const float* X = isQ ? dec : enc;

  // ---- async X staging: 6 DMA per wave, source-swizzled ----
  const char* Xb = (const char*)(X + (size_t)m0 * EMBED);
#pragma unroll
  for (int j = 0; j < 6; ++j) {
    const int k = w * 6 + j;                 // chunk 0..47 (wave-uniform)
    const int row = k / 3, part = k - row * 3;
    const int co = part * 1024 + (lane << 4);
    const int src = row * 3072 + (co ^ ((row & 7) << 4));
    gload16(Xb + src, smem + row * 4096 + part * 1024);
  }

  // ---- W fragments -> live registers (parallel-issue; L2-resident) ----
  const size_t wrow = (size_t)(c * 16 + fr) * EMBED + g * 384 + fg * 8;
  s16x8 wf1[12], wf2[12];
  if (isQ) {
    const short* wb = wbuf + wrow;
#pragma unroll
    for (int s = 0; s < 12; ++s)
      wf1[s] = *reinterpret_cast<const s16x8*>(wb + s * 32);
  } else {
    const short* wk = wbuf + WELEM + wrow;
    const short* wv = wbuf + 2 * (size_t)WELEM + wrow;
#pragma unroll
    for (int s = 0; s < 12; ++s) {
      wf1[s] = *reinterpret_cast<const s16x8*>(wk + s * 32);
      wf2[s] = *reinterpret_cast<const s16x8*>(wv + s * 32);
    }
  }
  __syncthreads();   // drains DMA (vmcnt) + W loads

  // ---- 12 MFMA steps; X frag = 2x ds_read_b128 fp32 + cvt ----
  const int swr = (fr & 7) << 4;
  const char* xrow = smem + fr * 4096;
  fx4 acc1 = fx4{0.f, 0.f, 0.f, 0.f};
  fx4 acc2 = fx4{0.f, 0.f, 0.f, 0.f};
#pragma unroll
  for (int s = 0; s < 12; ++s) {
    const int cb = g * 1536 + s * 128 + fg * 32;
    fx4 xlo = *reinterpret_cast<const fx4*>(xrow + (cb ^ swr));
    fx4 xhi = *reinterpret_cast<const fx4*>(xrow + ((cb + 16) ^ swr));
    s16x8 xa = cvt8(xlo, xhi);
    acc1 = mfma16(wf1[s], xa, acc1);
    if (!isQ) acc2 = mfma16(wf2[s], xa, acc2);
  }

  // ---- K-half reduce through LDS (disjoint region; X reads done) ----
  const int ridx = fr * 64 + c * 16 + fg * 4;
  if (g == 0) {
    *reinterpret_cast<fx4*>(&Red1[ridx]) = acc1;
    if (!isQ) *reinterpret_cast<fx4*>(&Red2[ridx]) = acc2;
  }
  __syncthreads();
  if (g == 1) {
    fx4 p1 = *reinterpret_cast<const fx4*>(&Red1[ridx]);
    if (isQ) {
      fx4 b4 = *reinterpret_cast<const fx4*>(bq + c * 16 + fg * 4);
      *reinterpret_cast<s16x4*>(Qout + (size_t)(m0 + fr) * HD + c * 16 + fg * 4) =
          cvt4(acc1[0] + p1[0] + b4[0], acc1[1] + p1[1] + b4[1],
               acc1[2] + p1[2] + b4[2], acc1[3] + p1[3] + b4[3]);
    } else {
      fx4 p2 = *reinterpret_cast<const fx4*>(&Red2[ridx]);
      fx4 bk4 = *reinterpret_cast<const fx4*>(bk + c * 16 + fg * 4);
      *reinterpret_cast<s16x4*>(Kout + (size_t)(m0 + fr) * HD + c * 16 + fg * 4) =
          cvt4(acc1[0] + p1[0] + bk4[0], acc1[1] + p1[1] + bk4[1],
               acc1[2] + p1[2] + bk4[2], acc1[3] + p1[3] + bk4[3]);
      fx4 bv4 = *reinterpret_cast<const fx4*>(bv + c * 16 + fg * 4);
      const int bidx = m0 >> 10;             // 16 | 1024: no batch straddle
      const int kvp  = (m0 & 1023) + fr;
#pragma unroll
      for (int r = 0; r < 4; ++r) {
        const int d = c * 16 + fg * 4 + r;
        VT[((size_t)(bidx * HD + d)) * LEN + kvp] =
            (short)pk2(acc2[r] + p2[r] + bv4[r], 0.f);
      }
    }
  }
}

// ---------------------------------------------------------------------------
// Fused flash attention (unchanged; ~3 us). 1024 threads = 16 waves =
// 4 KV-groups x 4 q-waves; K/V LDS-staged per group; lane-local softmax;
// partial combine through LDS overlay.
// ---------------------------------------------------------------------------
__global__ __launch_bounds__(1024, 4) void attn_kernel(
    const short* __restrict__ Q, const short* __restrict__ K,
    const short* __restrict__ VT, float* __restrict__ Out)
{
  __shared__ __align__(16) char smem[110592];
  short (*Kls)[64][72]  = reinterpret_cast<short(*)[64][72]>(smem);
  short (*Vls)[64][72]  = reinterpret_cast<short(*)[64][72]>(smem + 36864);
  short (*Plds)[16][72] = reinterpret_cast<short(*)[16][72]>(smem + 73728);
  float (*HL)[64][68]   = reinterpret_cast<float(*)[64][68]>(smem);
  float2 (*ML)[64]      = reinterpret_cast<float2(*)[64]>(smem + 69632);

  const int t = threadIdx.x, lane = t & 63, w = t >> 6;
  const int g = w >> 2, wl = w & 3;
  const int fr = lane & 15, fg = lane >> 4;
  const int xcd = blockIdx.x & 7;
  const int idx = blockIdx.x >> 3;        // 0..31
  const int b   = xcd + ((idx & 1) << 3);
  const int q0  = (idx >> 1) * 64;
  const int qrow = q0 + wl * 16;

  const short* Qb  = Q  + (size_t)b * LEN * HD;
  const short* Kb  = K  + ((size_t)b * LEN + g * KVQ) * HD;
  const short* VTb = VT + (size_t)b * HD * LEN + g * KVQ;

  s16x8 qa0 = *reinterpret_cast<const s16x8*>(Qb + (size_t)(qrow + fr) * HD + fg * 8);
  s16x8 qa1 = *reinterpret_cast<const s16x8*>(Qb + (size_t)(qrow + fr) * HD + 32 + fg * 8);

  fx4 hacc[4];
#pragma unroll
  for (int c = 0; c < 4; ++c) hacc[c] = fx4{0.f, 0.f, 0.f, 0.f};
  float mrun = -1e30f, lsum = 0.f;
  const float SC = 0.125f * 1.44269504088896340736f;  // 1/sqrt(64) * log2(e)

  const int u = t & 255;
  const int srow = u >> 2;          // 0..63
  const int sch  = (u & 3) * 16;    // short col offset: 0,16,32,48 (32B/lane)

  s16x8 pk0 = *reinterpret_cast<const s16x8*>(Kb + (size_t)srow * HD + sch);
  s16x8 pk1 = *reinterpret_cast<const s16x8*>(Kb + (size_t)srow * HD + sch + 8);
  s16x8 pv0 = *reinterpret_cast<const s16x8*>(VTb + (size_t)srow * LEN + sch);
  s16x8 pv1 = *reinterpret_cast<const s16x8*>(VTb + (size_t)srow * LEN + sch + 8);
  *reinterpret_cast<s16x8*>(&Kls[g][srow][sch])     = pk0;
  *reinterpret_cast<s16x8*>(&Kls[g][srow][sch + 8]) = pk1;
  *reinterpret_cast<s16x8*>(&Vls[g][srow][sch])     = pv0;
  *reinterpret_cast<s16x8*>(&Vls[g][srow][sch + 8]) = pv1;
  __syncthreads();

#pragma unroll
  for (int it = 0; it < KVQ / 64; ++it) {
    if (it + 1 < KVQ / 64) {  // issue next tile's loads before compute
      const int nk = (it + 1) * 64;
      pk0 = *reinterpret_cast<const s16x8*>(Kb + (size_t)(nk + srow) * HD + sch);
      pk1 = *reinterpret_cast<const s16x8*>(Kb + (size_t)(nk + srow) * HD + sch + 8);
      pv0 = *reinterpret_cast<const s16x8*>(VTb + (size_t)srow * LEN + nk + sch);
      pv1 = *reinterpret_cast<const s16x8*>(VTb + (size_t)srow * LEN + nk + sch + 8);
    }
    fx4 sacc[4];
#pragma unroll
    for (int s = 0; s < 4; ++s) {
      s16x8 kf0 = *reinterpret_cast<const s16x8*>(&Kls[g][s * 16 + fr][fg * 8]);
      s16x8 kf1 = *reinterpret_cast<const s16x8*>(&Kls[g][s * 16 + fr][32 + fg * 8]);
      fx4 z = fx4{0.f, 0.f, 0.f, 0.f};
      z = mfma16(kf0, qa0, z);
      sacc[s] = mfma16(kf1, qa1, z);
    }
    float xs[4][4];
    float xm = -1e30f;
#pragma unroll
    for (int s = 0; s < 4; ++s)
#pragma unroll
      for (int r = 0; r < 4; ++r) {
        xs[s][r] = sacc[s][r] * SC;
        xm = fmaxf(xm, xs[s][r]);
      }
    xm = fmaxf(xm, __shfl_xor(xm, 16, 64));
    xm = fmaxf(xm, __shfl_xor(xm, 32, 64));
    const float mn = fmaxf(mrun, xm);
    const float corr = __builtin_amdgcn_exp2f(mrun - mn);
    mrun = mn;
    float ps = 0.f;
#pragma unroll
    for (int s = 0; s < 4; ++s) {
      float p[4];
#pragma unroll
      for (int r = 0; r < 4; ++r) {
        p[r] = __builtin_amdgcn_exp2f(xs[s][r] - mn);
        ps += p[r];
      }
      *reinterpret_cast<s16x4*>(&Plds[w][fr][s * 16 + fg * 4]) =
          cvt4(p[0], p[1], p[2], p[3]);
    }
    ps += __shfl_xor(ps, 16, 64);
    ps += __shfl_xor(ps, 32, 64);
    lsum = lsum * corr + ps;
    __builtin_amdgcn_wave_barrier();
    s16x8 pa0 = *reinterpret_cast<const s16x8*>(&Plds[w][fr][fg * 8]);
    s16x8 pa1 = *reinterpret_cast<const s16x8*>(&Plds[w][fr][32 + fg * 8]);
#pragma unroll
    for (int c = 0; c < 4; ++c) {
      s16x8 vf0 = *reinterpret_cast<const s16x8*>(&Vls[g][c * 16 + fr][fg * 8]);
      s16x8 vf1 = *reinterpret_cast<const s16x8*>(&Vls[g][c * 16 + fr][32 + fg * 8]);
      fx4 h = hacc[c];
#pragma unroll
      for (int r = 0; r < 4; ++r) h[r] *= corr;
      h = mfma16(vf0, pa0, h);
      hacc[c] = mfma16(vf1, pa1, h);
    }
    __syncthreads();  // all waves done reading tile it
    if (it + 1 < KVQ / 64) {
      *reinterpret_cast<s16x8*>(&Kls[g][srow][sch])     = pk0;
      *reinterpret_cast<s16x8*>(&Kls[g][srow][sch + 8]) = pk1;
      *reinterpret_cast<s16x8*>(&Vls[g][srow][sch])     = pv0;
      *reinterpret_cast<s16x8*>(&Vls[g][srow][sch + 8]) = pv1;
    }
    __syncthreads();  // tile it+1 visible
  }
#pragma unroll
  for (int c = 0; c < 4; ++c)
    *reinterpret_cast<fx4*>(&HL[g][wl * 16 + fr][c * 16 + fg * 4]) = hacc[c];
  if (fg == 0) ML[g][wl * 16 + fr] = make_float2(mrun, lsum);
  __syncthreads();
  const int row = t >> 4, d0 = (t & 15) * 4;
  const float2 s0 = ML[0][row], s1 = ML[1][row], s2 = ML[2][row], s3 = ML[3][row];
  const float mm = fmaxf(fmaxf(s0.x, s1.x), fmaxf(s2.x, s3.x));
  const float w0 = __builtin_amdgcn_exp2f(s0.x - mm);
  const float w1 = __builtin_amdgcn_exp2f(s1.x - mm);
  const float w2 = __builtin_amdgcn_exp2f(s2.x - mm);
  const float w3 = __builtin_amdgcn_exp2f(s3.x - mm);
  const float inv = 1.0f / (s0.y * w0 + s1.y * w1 + s2.y * w2 + s3.y * w3);
  fx4 h0 = *reinterpret_cast<const fx4*>(&HL[0][row][d0]);
  fx4 h1 = *reinterpret_cast<const fx4*>(&HL[1][row][d0]);
  fx4 h2 = *reinterpret_cast<const fx4*>(&HL[2][row][d0]);
  fx4 h3 = *reinterpret_cast<const fx4*>(&HL[3][row][d0]);
  fx4 o;
#pragma unroll
  for (int r = 0; r < 4; ++r)
    o[r] = (h0[r] * w0 + h1[r] * w1 + h2[r] * w2 + h3[r] * w3) * inv;
  *reinterpret_cast<fx4*>(Out + ((size_t)b * LEN + q0 + row) * HD + d0) = o;
}

extern "C" void kernel_launch(void* const* d_in, const int* in_sizes, int n_in,
                              void* d_out, int out_size, void* d_ws, size_t ws_size,
                              hipStream_t stream) {
  const float* dec = (const float*)d_in[0];
  const float* enc = (const float*)d_in[1];
  const float* Wq  = (const float*)d_in[2];
  const float* bq  = (const float*)d_in[3];
  const float* Wk  = (const float*)d_in[4];
  const float* bk  = (const float*)d_in[5];
  const float* Wv  = (const float*)d_in[6];
  const float* bv  = (const float*)d_in[7];
  float* out = (float*)d_out;

  short* qws  = (short*)d_ws;                        // [16384,64] bf16
  short* kws  = qws + (size_t)M_TOT * HD;            // [16384,64] bf16
  short* vtws = kws + (size_t)M_TOT * HD;            // [16,64,1024] bf16
  short* wbuf = vtws + (size_t)NB * HD * LEN;        // [3][49152] bf16 weights

  convert_w_kernel<<<(3 * WELEM / 8) / 256, 256, 0, stream>>>(Wq, Wk, Wv, wbuf);
  proj_kernel<<<2 * (M_TOT / 16), 512, 0, stream>>>(
      dec, enc, wbuf, bq, bk, bv, qws, kws, vtws);
  attn_kernel<<<NB * (LEN / 64), 1024, 0, stream>>>(qws, kws, vtws, out);
}

// Round 11
// 39.500 us; speedup vs baseline: 1.6332x; 1.6332x over previous
//
#include <hip/hip_runtime.h>
#include <hip/hip_bf16.h>

typedef __attribute__((ext_vector_type(8))) short s16x8;
typedef __attribute__((ext_vector_type(4))) short s16x4;
typedef __attribute__((ext_vector_type(4))) float fx4;

#define DEVINL __device__ __forceinline__

constexpr int EMBED = 768;
constexpr int HD    = 64;
constexpr int NB    = 16;
constexpr int LEN   = 1024;
constexpr int M_TOT = NB * LEN;   // 16384
constexpr int KVQ   = LEN / 4;    // 256 kv per group in fused attn
constexpr int WELEM = HD * EMBED; // 49152
constexpr int BM    = 64;
constexpr int NSTEP = EMBED / 32; // 24

// fp32 -> bf16 RNE via v_cvt_pk_bf16_f32 (2 elems/inst).
DEVINL unsigned pk2(float lo, float hi) {
  __hip_bfloat162 h = __float22bfloat162_rn(float2{lo, hi});
  union { __hip_bfloat162 h; unsigned u; } c; c.h = h;
  return c.u;
}
DEVINL s16x8 cvt8(fx4 a, fx4 b) {
  union { unsigned u[4]; s16x8 v; } r;
  r.u[0] = pk2(a[0], a[1]); r.u[1] = pk2(a[2], a[3]);
  r.u[2] = pk2(b[0], b[1]); r.u[3] = pk2(b[2], b[3]);
  return r.v;
}
DEVINL s16x4 cvt4(float a0, float a1, float a2, float a3) {
  union { unsigned u[2]; s16x4 v; } r;
  r.u[0] = pk2(a0, a1); r.u[1] = pk2(a2, a3);
  return r.v;
}

DEVINL fx4 mfma16(s16x8 a, s16x8 b, fx4 c) {
  return __builtin_amdgcn_mfma_f32_16x16x32_bf16(a, b, c, 0, 0, 0);
}

// async global->LDS DMA, 16B/lane; LDS dest = wave-uniform base + lane*16,
// global source = per-lane (enables source-side swizzle, m173 pattern).
DEVINL void gload16(const void* g, void* l) {
  __builtin_amdgcn_global_load_lds(
      (const __attribute__((address_space(1))) void*)g,
      (__attribute__((address_space(3))) void*)l, 16, 0, 0);
}

// ---------------------------------------------------------------------------
// One-shot: convert Wq|Wk|Wv (each 64x768 fp32) to bf16, packed [3][49152].
// ---------------------------------------------------------------------------
__global__ __launch_bounds__(256) void convert_w_kernel(
    const float* __restrict__ a, const float* __restrict__ b,
    const float* __restrict__ c, short* __restrict__ out)
{
  const int gid = blockIdx.x * 256 + threadIdx.x;   // 18432 threads, 8 elem each
  const int seg = gid / (WELEM / 8);
  const int off = (gid % (WELEM / 8)) * 8;
  const float* src = (seg == 0) ? a : (seg == 1) ? b : c;
  fx4 v0 = *reinterpret_cast<const fx4*>(src + off);
  fx4 v1 = *reinterpret_cast<const fx4*>(src + off + 4);
  *reinterpret_cast<s16x8*>(out + (size_t)seg * WELEM + off) = cvt8(v0, v1);
}

// ---------------------------------------------------------------------------
// Round-11 projection: m97-style STEP-LOOP pipeline (the HW-proven staging
// structure). 512 blocks x 256 thr: [0,256) Q from dec, [256,512) K+V^T from
// enc. BM=64 rows/block, 24 K-steps of BK=32, double-buffered LDS.
// Per step: STAGE(next tile via global_load_lds) -> ds_read+MFMA(current)
// -> __syncthreads. Loads re-issued EVERY step for 24 steps -> the CU memory
// queue never drains (the r6-r10 single-burst designs idled it ~80%).
//   X staged fp32 (8KB/step), source-XOR swizzle (row&7)<<4 -> 2-way on read.
//   W staged bf16 (4KB/step each), swizzle (row&3)<<4 -> 4-way (acceptable).
//   Each wave: 16 m-rows, full N=64, full K accumulate -> no reduce phase.
// ---------------------------------------------------------------------------
__global__ __launch_bounds__(256, 4) void proj_kernel(
    const float* __restrict__ dec, const float* __restrict__ enc,
    const short* __restrict__ wbuf,   // [3][WELEM] bf16: Wq | Wk | Wv
    const float* __restrict__ bq, const float* __restrict__ bk,
    const float* __restrict__ bv,
    short* __restrict__ Qout, short* __restrict__ Kout,
    short* __restrict__ VT)
{
  // buffer b at smem + b*16384:
  //   X  [64 rows][128 B] @ 0     (8 KB, fp32, swizzled)
  //   W1 [64 rows][64 B]  @ 8192  (4 KB, bf16, swizzled)
  //   W2 [64 rows][64 B]  @ 12288 (4 KB, bf16, KV only)
  __shared__ __align__(16) char smem[32768];

  const int t = threadIdx.x, lane = t & 63, w = t >> 6;
  const int fr = lane & 15, fg = lane >> 4;
  const bool isQ = blockIdx.x < 256u;
  const int bx = isQ ? blockIdx.x : blockIdx.x - 256;
  const int m0 = bx * BM;
  const float* X = isQ ? dec : enc;
  const char* Xg  = (const char*)(X + (size_t)m0 * EMBED);
  const char* W1g = (const char*)(isQ ? wbuf : wbuf + WELEM);
  const char* W2g = (const char*)(wbuf + 2 * (size_t)WELEM);

  // per-lane source-address components (constant over steps)
  const int xp   = w * 2048 + lane * 16;          // covers 2 gload instrs
  const int xrow0 = xp >> 7;                      // row of 1st instr's lane
  const int xrow1 = (xp + 1024) >> 7;
  const int xcol0 = xp & 127, xcol1 = (xp + 1024) & 127;
  const int xsrc0 = xrow0 * 3072 + (xcol0 ^ ((xrow0 & 7) << 4));
  const int xsrc1 = xrow1 * 3072 + (xcol1 ^ ((xrow1 & 7) << 4));
  const int wp   = w * 1024 + lane * 16;
  const int wrow = wp >> 6, wcol = wp & 63;
  const int wsrc = wrow * 1536 + (wcol ^ ((wrow & 3) << 4));

  fx4 acc1[4], acc2[4];
#pragma unroll
  for (int j = 0; j < 4; ++j) {
    acc1[j] = fx4{0.f, 0.f, 0.f, 0.f};
    acc2[j] = fx4{0.f, 0.f, 0.f, 0.f};
  }

  // fragment-read constants
  const int xr = w * 16 + fr;                     // this lane's m-row in tile
  const int xsw = (xr & 7) << 4;
  const char* xbase0; const char* wbase0;

  // prologue: stage step 0
  {
    char* b0 = smem;
    gload16(Xg + xsrc0, b0 + w * 2048);
    gload16(Xg + xsrc1 + 0, b0 + w * 2048 + 1024);
    gload16(W1g + wsrc, b0 + 8192 + w * 1024);
    if (!isQ) gload16(W2g + wsrc, b0 + 12288 + w * 1024);
  }
  __syncthreads();

#pragma unroll 2
  for (int k = 0; k < NSTEP; ++k) {
    char* cur = smem + (k & 1) * 16384;
    // ---- stage next step into the other buffer (read-done via last barrier)
    if (k + 1 < NSTEP) {
      char* nxt = smem + ((k + 1) & 1) * 16384;
      const int ko = (k + 1) * 128;               // X byte col offset
      const int kw = (k + 1) * 64;                // W byte col offset
      gload16(Xg + ko + xsrc0, nxt + w * 2048);
      gload16(Xg + ko + xsrc1, nxt + w * 2048 + 1024);
      gload16(W1g + kw + wsrc, nxt + 8192 + w * 1024);
      if (!isQ) gload16(W2g + kw + wsrc, nxt + 12288 + w * 1024);
    }
    // ---- compute current step ----
    const char* xrb = cur + xr * 128;
    fx4 xlo = *reinterpret_cast<const fx4*>(xrb + ((fg * 32) ^ xsw));
    fx4 xhi = *reinterpret_cast<const fx4*>(xrb + ((fg * 32 + 16) ^ xsw));
    s16x8 xa = cvt8(xlo, xhi);
#pragma unroll
    for (int j = 0; j < 4; ++j) {
      const int wr = j * 16 + fr;
      const int wo = wr * 64 + ((fg * 16) ^ ((wr & 3) << 4));
      s16x8 wf1 = *reinterpret_cast<const s16x8*>(cur + 8192 + wo);
      acc1[j] = mfma16(wf1, xa, acc1[j]);
      if (!isQ) {
        s16x8 wf2 = *reinterpret_cast<const s16x8*>(cur + 12288 + wo);
        acc2[j] = mfma16(wf2, xa, acc2[j]);
      }
    }
    __syncthreads();   // waves done with cur; next-tile loads drained
  }

  // ---- epilogue: D[n][m]: n = j*16+fg*4+r, m-col = fr -> m = m0+w*16+fr ----
  const int m = m0 + w * 16 + fr;
  if (isQ) {
#pragma unroll
    for (int j = 0; j < 4; ++j) {
      fx4 bb = *reinterpret_cast<const fx4*>(bq + j * 16 + fg * 4);
      *reinterpret_cast<s16x4*>(Qout + (size_t)m * HD + j * 16 + fg * 4) =
          cvt4(acc1[j][0] + bb[0], acc1[j][1] + bb[1],
               acc1[j][2] + bb[2], acc1[j][3] + bb[3]);
    }
  } else {
#pragma unroll
    for (int j = 0; j < 4; ++j) {
      fx4 bb = *reinterpret_cast<const fx4*>(bk + j * 16 + fg * 4);
      *reinterpret_cast<s16x4*>(Kout + (size_t)m * HD + j * 16 + fg * 4) =
          cvt4(acc1[j][0] + bb[0], acc1[j][1] + bb[1],
               acc1[j][2] + bb[2], acc1[j][3] + bb[3]);
    }
    const int bidx = m0 >> 10;                    // 64 | 1024: no straddle
    const int kvp  = (m0 & 1023) + w * 16 + fr;
#pragma unroll
    for (int j = 0; j < 4; ++j) {
      fx4 bb = *reinterpret_cast<const fx4*>(bv + j * 16 + fg * 4);
#pragma unroll
      for (int r = 0; r < 4; ++r) {
        const int d = j * 16 + fg * 4 + r;
        VT[((size_t)(bidx * HD + d)) * LEN + kvp] =
            (short)pk2(acc2[j][r] + bb[r], 0.f);
      }
    }
  }
}

// ---------------------------------------------------------------------------
// Fused flash attention (unchanged; ~3 us). 1024 threads = 16 waves =
// 4 KV-groups x 4 q-waves; K/V LDS-staged per group; lane-local softmax;
// partial combine through LDS overlay.
// ---------------------------------------------------------------------------
__global__ __launch_bounds__(1024, 4) void attn_kernel(
    const short* __restrict__ Q, const short* __restrict__ K,
    const short* __restrict__ VT, float* __restrict__ Out)
{
  __shared__ __align__(16) char smem[110592];
  short (*Kls)[64][72]  = reinterpret_cast<short(*)[64][72]>(smem);
  short (*Vls)[64][72]  = reinterpret_cast<short(*)[64][72]>(smem + 36864);
  short (*Plds)[16][72] = reinterpret_cast<short(*)[16][72]>(smem + 73728);
  float (*HL)[64][68]   = reinterpret_cast<float(*)[64][68]>(smem);
  float2 (*ML)[64]      = reinterpret_cast<float2(*)[64]>(smem + 69632);

  const int t = threadIdx.x, lane = t & 63, w = t >> 6;
  const int g = w >> 2, wl = w & 3;
  const int fr = lane & 15, fg = lane >> 4;
  const int xcd = blockIdx.x & 7;
  const int idx = blockIdx.x >> 3;        // 0..31
  const int b   = xcd + ((idx & 1) << 3);
  const int q0  = (idx >> 1) * 64;
  const int qrow = q0 + wl * 16;

  const short* Qb  = Q  + (size_t)b * LEN * HD;
  const short* Kb  = K  + ((size_t)b * LEN + g * KVQ) * HD;
  const short* VTb = VT + (size_t)b * HD * LEN + g * KVQ;

  s16x8 qa0 = *reinterpret_cast<const s16x8*>(Qb + (size_t)(qrow + fr) * HD + fg * 8);
  s16x8 qa1 = *reinterpret_cast<const s16x8*>(Qb + (size_t)(qrow + fr) * HD + 32 + fg * 8);

  fx4 hacc[4];
#pragma unroll
  for (int c = 0; c < 4; ++c) hacc[c] = fx4{0.f, 0.f, 0.f, 0.f};
  float mrun = -1e30f, lsum = 0.f;
  const float SC = 0.125f * 1.44269504088896340736f;  // 1/sqrt(64) * log2(e)

  const int u = t & 255;
  const int srow = u >> 2;          // 0..63
  const int sch  = (u & 3) * 16;    // short col offset: 0,16,32,48 (32B/lane)

  s16x8 pk0 = *reinterpret_cast<const s16x8*>(Kb + (size_t)srow * HD + sch);
  s16x8 pk1 = *reinterpret_cast<const s16x8*>(Kb + (size_t)srow * HD + sch + 8);
  s16x8 pv0 = *reinterpret_cast<const s16x8*>(VTb + (size_t)srow * LEN + sch);
  s16x8 pv1 = *reinterpret_cast<const s16x8*>(VTb + (size_t)srow * LEN + sch + 8);
  *reinterpret_cast<s16x8*>(&Kls[g][srow][sch])     = pk0;
  *reinterpret_cast<s16x8*>(&Kls[g][srow][sch + 8]) = pk1;
  *reinterpret_cast<s16x8*>(&Vls[g][srow][sch])     = pv0;
  *reinterpret_cast<s16x8*>(&Vls[g][srow][sch + 8]) = pv1;
  __syncthreads();

#pragma unroll
  for (int it = 0; it < KVQ / 64; ++it) {
    if (it + 1 < KVQ / 64) {  // issue next tile's loads before compute
      const int nk = (it + 1) * 64;
      pk0 = *reinterpret_cast<const s16x8*>(Kb + (size_t)(nk + srow) * HD + sch);
      pk1 = *reinterpret_cast<const s16x8*>(Kb + (size_t)(nk + srow) * HD + sch + 8);
      pv0 = *reinterpret_cast<const s16x8*>(VTb + (size_t)srow * LEN + nk + sch);
      pv1 = *reinterpret_cast<const s16x8*>(VTb + (size_t)srow * LEN + nk + sch + 8);
    }
    fx4 sacc[4];
#pragma unroll
    for (int s = 0; s < 4; ++s) {
      s16x8 kf0 = *reinterpret_cast<const s16x8*>(&Kls[g][s * 16 + fr][fg * 8]);
      s16x8 kf1 = *reinterpret_cast<const s16x8*>(&Kls[g][s * 16 + fr][32 + fg * 8]);
      fx4 z = fx4{0.f, 0.f, 0.f, 0.f};
      z = mfma16(kf0, qa0, z);
      sacc[s] = mfma16(kf1, qa1, z);
    }
    float xs[4][4];
    float xm = -1e30f;
#pragma unroll
    for (int s = 0; s < 4; ++s)
#pragma unroll
      for (int r = 0; r < 4; ++r) {
        xs[s][r] = sacc[s][r] * SC;
        xm = fmaxf(xm, xs[s][r]);
      }
    xm = fmaxf(xm, __shfl_xor(xm, 16, 64));
    xm = fmaxf(xm, __shfl_xor(xm, 32, 64));
    const float mn = fmaxf(mrun, xm);
    const float corr = __builtin_amdgcn_exp2f(mrun - mn);
    mrun = mn;
    float ps = 0.f;
#pragma unroll
    for (int s = 0; s < 4; ++s) {
      float p[4];
#pragma unroll
      for (int r = 0; r < 4; ++r) {
        p[r] = __builtin_amdgcn_exp2f(xs[s][r] - mn);
        ps += p[r];
      }
      *reinterpret_cast<s16x4*>(&Plds[w][fr][s * 16 + fg * 4]) =
          cvt4(p[0], p[1], p[2], p[3]);
    }
    ps += __shfl_xor(ps, 16, 64);
    ps += __shfl_xor(ps, 32, 64);
    lsum = lsum * corr + ps;
    __builtin_amdgcn_wave_barrier();
    s16x8 pa0 = *reinterpret_cast<const s16x8*>(&Plds[w][fr][fg * 8]);
    s16x8 pa1 = *reinterpret_cast<const s16x8*>(&Plds[w][fr][32 + fg * 8]);
#pragma unroll
    for (int c = 0; c < 4; ++c) {
      s16x8 vf0 = *reinterpret_cast<const s16x8*>(&Vls[g][c * 16 + fr][fg * 8]);
      s16x8 vf1 = *reinterpret_cast<const s16x8*>(&Vls[g][c * 16 + fr][32 + fg * 8]);
      fx4 h = hacc[c];
#pragma unroll
      for (int r = 0; r < 4; ++r) h[r] *= corr;
      h = mfma16(vf0, pa0, h);
      hacc[c] = mfma16(vf1, pa1, h);
    }
    __syncthreads();  // all waves done reading tile it
    if (it + 1 < KVQ / 64) {
      *reinterpret_cast<s16x8*>(&Kls[g][srow][sch])     = pk0;
      *reinterpret_cast<s16x8*>(&Kls[g][srow][sch + 8]) = pk1;
      *reinterpret_cast<s16x8*>(&Vls[g][srow][sch])     = pv0;
      *reinterpret_cast<s16x8*>(&Vls[g][srow][sch + 8]) = pv1;
    }
    __syncthreads();  // tile it+1 visible
  }
#pragma unroll
  for (int c = 0; c < 4; ++c)
    *reinterpret_cast<fx4*>(&HL[g][wl * 16 + fr][c * 16 + fg * 4]) = hacc[c];
  if (fg == 0) ML[g][wl * 16 + fr] = make_float2(mrun, lsum);
  __syncthreads();
  const int row = t >> 4, d0 = (t & 15) * 4;
  const float2 s0 = ML[0][row], s1 = ML[1][row], s2 = ML[2][row], s3 = ML[3][row];
  const float mm = fmaxf(fmaxf(s0.x, s1.x), fmaxf(s2.x, s3.x));
  const float w0 = __builtin_amdgcn_exp2f(s0.x - mm);
  const float w1 = __builtin_amdgcn_exp2f(s1.x - mm);
  const float w2 = __builtin_amdgcn_exp2f(s2.x - mm);
  const float w3 = __builtin_amdgcn_exp2f(s3.x - mm);
  const float inv = 1.0f / (s0.y * w0 + s1.y * w1 + s2.y * w2 + s3.y * w3);
  fx4 h0 = *reinterpret_cast<const fx4*>(&HL[0][row][d0]);
  fx4 h1 = *reinterpret_cast<const fx4*>(&HL[1][row][d0]);
  fx4 h2 = *reinterpret_cast<const fx4*>(&HL[2][row][d0]);
  fx4 h3 = *reinterpret_cast<const fx4*>(&HL[3][row][d0]);
  fx4 o;
#pragma unroll
  for (int r = 0; r < 4; ++r)
    o[r] = (h0[r] * w0 + h1[r] * w1 + h2[r] * w2 + h3[r] * w3) * inv;
  *reinterpret_cast<fx4*>(Out + ((size_t)b * LEN + q0 + row) * HD + d0) = o;
}

extern "C" void kernel_launch(void* const* d_in, const int* in_sizes, int n_in,
                              void* d_out, int out_size, void* d_ws, size_t ws_size,
                              hipStream_t stream) {
  const float* dec = (const float*)d_in[0];
  const float* enc = (const float*)d_in[1];
  const float* Wq  = (const float*)d_in[2];
  const float* bq  = (const float*)d_in[3];
  const float* Wk  = (const float*)d_in[4];
  const float* bk  = (const float*)d_in[5];
  const float* Wv  = (const float*)d_in[6];
  const float* bv  = (const float*)d_in[7];
  float* out = (float*)d_out;

  short* qws  = (short*)d_ws;                        // [16384,64] bf16
  short* kws  = qws + (size_t)M_TOT * HD;            // [16384,64] bf16
  short* vtws = kws + (size_t)M_TOT * HD;            // [16,64,1024] bf16
  short* wbuf = vtws + (size_t)NB * HD * LEN;        // [3][49152] bf16 weights

  convert_w_kernel<<<(3 * WELEM / 8) / 256, 256, 0, stream>>>(Wq, Wk, Wv, wbuf);
  proj_kernel<<<512, 256, 0, stream>>>(
      dec, enc, wbuf, bq, bk, bv, qws, kws, vtws);
  attn_kernel<<<NB * (LEN / 64), 1024, 0, stream>>>(qws, kws, vtws, out);
}